// Round 3
// baseline (355.524 us; speedup 1.0000x reference)
//
#include <hip/hip_runtime.h>
#include <hip/hip_bf16.h>

// Problem constants
#define T_TOK 2048
#define HID   1024
#define FF    3584
#define NE    8
#define TOPK  2

typedef __bf16 bf16x8 __attribute__((ext_vector_type(8)));
typedef float  f32x4  __attribute__((ext_vector_type(4)));
typedef unsigned short u16x8 __attribute__((ext_vector_type(8)));

// ---- workspace layout (bytes) ----
#define WS_COUNTS   0u
#define WS_OFFSETS  64u
#define WS_TILECNT  128u          // int[2]: n1 (BM=512), n2 (BM=256)
#define WS_TLE1     256u          // int[64]
#define WS_TLM1     512u          // int[64]
#define WS_TLE2     768u          // int[64]
#define WS_TLM2     1024u         // int[64]
#define WS_TOPKI    4096u         // int[4096]
#define WS_TOPKW    20480u        // float[4096]
#define WS_SLOTPOS  36864u        // int[4096]
#define WS_SLOTROW  53248u        // int[4096]
#define WS_ROUTETOK 69632u        // int[4096]
#define WS_XBF      131072u                           // ushort[2048*1024] (4 MB)
#define WS_ACT      (WS_XBF + 2048u*1024u*2u)         // ushort[4096*3584] (29.4 MB)
#define WS_Y        (WS_ACT + 4096u*3584u*2u)         // float[2*4096*1024] (32 MB)
// total ~64.1 MB

static __device__ __forceinline__ unsigned short f2bf(float f) {
    unsigned int u = __builtin_bit_cast(unsigned int, f);
    u += 0x7FFFu + ((u >> 16) & 1u);   // RNE
    return (unsigned short)(u >> 16);
}
// round-half-up pack of 2 floats -> 2 bf16 in one u32
static __device__ __forceinline__ unsigned int pack2(float a, float b) {
    unsigned int ua = __builtin_bit_cast(unsigned int, a) + 0x8000u;
    unsigned int ub = __builtin_bit_cast(unsigned int, b) + 0x8000u;
    return (ua >> 16) | (ub & 0xFFFF0000u);
}

// ---------------- router (fused x->bf16 convert) ----------------
__global__ __launch_bounds__(256) void k_router(
    const float* __restrict__ x, const float* __restrict__ gw,
    unsigned short* __restrict__ xb, int* __restrict__ counts,
    int* __restrict__ topki, float* __restrict__ topkw, int* __restrict__ slotpos)
{
    int t = blockIdx.x * 4 + (threadIdx.x >> 6);
    int l = threadIdx.x & 63;
    const float* xr = x + (size_t)t * HID;
    unsigned short* xbr = xb + (size_t)t * HID;
    float acc[NE];
#pragma unroll
    for (int e = 0; e < NE; ++e) acc[e] = 0.f;
#pragma unroll
    for (int i = 0; i < 4; ++i) {
        int h = l * 4 + i * 256;
        float4 xv = *(const float4*)(xr + h);
        ushort4 o;
        o.x = f2bf(xv.x); o.y = f2bf(xv.y); o.z = f2bf(xv.z); o.w = f2bf(xv.w);
        *(ushort4*)(xbr + h) = o;
#pragma unroll
        for (int e = 0; e < NE; ++e) {
            float4 g = *(const float4*)(gw + e * HID + h);
            acc[e] += xv.x * g.x + xv.y * g.y + xv.z * g.z + xv.w * g.w;
        }
    }
#pragma unroll
    for (int e = 0; e < NE; ++e) {
#pragma unroll
        for (int off = 32; off; off >>= 1) acc[e] += __shfl_xor(acc[e], off);
    }
    if (l == 0) {
        float best = -1e30f, second = -1e30f;
        int bi = 0, si = 0;
#pragma unroll
        for (int e = 0; e < NE; ++e) {
            float v = acc[e];
            if (v > best) { second = best; si = bi; best = v; bi = e; }
            else if (v > second) { second = v; si = e; }
        }
        float w0 = 1.f / (1.f + __expf(second - best));
        float w1 = 1.f - w0;
        topki[2 * t] = bi;  topki[2 * t + 1] = si;
        topkw[2 * t] = w0;  topkw[2 * t + 1] = w1;
        slotpos[2 * t]     = atomicAdd(&counts[bi], 1);
        slotpos[2 * t + 1] = atomicAdd(&counts[si], 1);
    }
}

// ---------------- prefix + two compact tile lists ----------------
__global__ void k_prefix(const int* __restrict__ counts, int* __restrict__ offsets,
                         int* __restrict__ tl1e, int* __restrict__ tl1m,
                         int* __restrict__ tl2e, int* __restrict__ tl2m,
                         int* __restrict__ tilecnt) {
    if (threadIdx.x == 0) {
        int o = 0;
#pragma unroll
        for (int e = 0; e < NE; ++e) { offsets[e] = o; o += counts[e]; }
        int n1 = 0, n2 = 0;
        for (int e = 0; e < NE; ++e) {
            int t1 = (counts[e] + 511) >> 9;
            for (int i = 0; i < t1; ++i) { tl1e[n1] = e; tl1m[n1] = i; ++n1; }
            int t2 = (counts[e] + 255) >> 8;
            for (int i = 0; i < t2; ++i) { tl2e[n2] = e; tl2m[n2] = i; ++n2; }
        }
        tilecnt[0] = n1; tilecnt[1] = n2;
    }
}

// ---------------- fill routing arrays ----------------
__global__ void k_fill(const int* __restrict__ topki, const int* __restrict__ slotpos,
                       const int* __restrict__ offsets, int* __restrict__ routetok,
                       int* __restrict__ slotrow) {
    int j = blockIdx.x * blockDim.x + threadIdx.x;
    if (j >= T_TOK * TOPK) return;
    int e = topki[j];
    int row = offsets[e] + slotpos[j];
    routetok[row] = j >> 1;
    slotrow[j] = row;
}

// ---------------- GEMM1: act = silu(Xe@w1^T) * (Xe@w3^T) ----------------
// BM=512 (weights read ~once), BN=64 per matrix, BK=64, 8 waves.
// A fragments loaded direct from global (xb is L2-resident), B reg-staged f32->bf16 LDS.
__global__ __launch_bounds__(512, 2) void k_gemm1(
    const unsigned short* __restrict__ xb, const float* __restrict__ w1,
    const float* __restrict__ w3, const int* __restrict__ counts,
    const int* __restrict__ offsets, const int* __restrict__ routetok,
    const int* __restrict__ tl1e, const int* __restrict__ tl1m,
    const int* __restrict__ tilecnt, unsigned short* __restrict__ act)
{
    int by = blockIdx.y;
    if (by >= tilecnt[0]) return;
    int e = tl1e[by];
    int rbase = tl1m[by] * 512;
    int cnt = counts[e], obase = offsets[e];
    int fbase = blockIdx.x * 64;

    __shared__ __align__(16) unsigned short lB1[64 * 72];
    __shared__ __align__(16) unsigned short lB3[64 * 72];
    __shared__ int ltok[512];

    int tid = threadIdx.x;
    {
        int r = rbase + tid;
        int rc = r < cnt ? r : cnt - 1;
        ltok[tid] = routetok[obase + rc];
    }
    __syncthreads();

    int lane = tid & 63, wv = tid >> 6;
    int klane = (lane >> 4) * 8;
    const char* xbb = (const char*)xb;
    unsigned int aoff[4];
#pragma unroll
    for (int m = 0; m < 4; ++m)
        aoff[m] = (unsigned int)ltok[wv * 64 + m * 16 + (lane & 15)] * (HID * 2);

    int rbr = tid >> 3, cbc = (tid & 7) * 8;
    const float* pb1 = w1 + ((size_t)e * FF + fbase + rbr) * HID + cbc;
    const float* pb3 = w3 + ((size_t)e * FF + fbase + rbr) * HID + cbc;

    f32x4 accg[4][4], accu[4][4];
#pragma unroll
    for (int m = 0; m < 4; ++m)
#pragma unroll
        for (int n = 0; n < 4; ++n) {
            accg[m][n] = (f32x4){0.f, 0.f, 0.f, 0.f};
            accu[m][n] = (f32x4){0.f, 0.f, 0.f, 0.f};
        }

    float4 r1a = *(const float4*)(pb1);
    float4 r1b = *(const float4*)(pb1 + 4);
    float4 r3a = *(const float4*)(pb3);
    float4 r3b = *(const float4*)(pb3 + 4);
    u16x8 a0[4], a1[4];
#pragma unroll
    for (int m = 0; m < 4; ++m)
        a0[m] = *(const u16x8*)(xbb + aoff[m] + klane * 2);

    for (int kt = 0; kt < HID / 64; ++kt) {
        uint2 p;
        p.x = pack2(r1a.x, r1a.y); p.y = pack2(r1a.z, r1a.w);
        *(uint2*)(lB1 + rbr * 72 + cbc) = p;
        p.x = pack2(r1b.x, r1b.y); p.y = pack2(r1b.z, r1b.w);
        *(uint2*)(lB1 + rbr * 72 + cbc + 4) = p;
        p.x = pack2(r3a.x, r3a.y); p.y = pack2(r3a.z, r3a.w);
        *(uint2*)(lB3 + rbr * 72 + cbc) = p;
        p.x = pack2(r3b.x, r3b.y); p.y = pack2(r3b.z, r3b.w);
        *(uint2*)(lB3 + rbr * 72 + cbc + 4) = p;
        __syncthreads();

        int kof = (kt + 1) * 64;
        if (kt < HID / 64 - 1) {
            r1a = *(const float4*)(pb1 + kof);
            r1b = *(const float4*)(pb1 + kof + 4);
            r3a = *(const float4*)(pb3 + kof);
            r3b = *(const float4*)(pb3 + kof + 4);
        }
        // prefetch A frags for kk=32
#pragma unroll
        for (int m = 0; m < 4; ++m)
            a1[m] = *(const u16x8*)(xbb + aoff[m] + (kt * 64 + 32 + klane) * 2);
        // kk = 0
        {
            bf16x8 b1f[4], b3f[4];
#pragma unroll
            for (int n = 0; n < 4; ++n) {
                b1f[n] = *(const bf16x8*)(lB1 + (n * 16 + (lane & 15)) * 72 + klane);
                b3f[n] = *(const bf16x8*)(lB3 + (n * 16 + (lane & 15)) * 72 + klane);
            }
#pragma unroll
            for (int m = 0; m < 4; ++m)
#pragma unroll
                for (int n = 0; n < 4; ++n) {
                    accg[m][n] = __builtin_amdgcn_mfma_f32_16x16x32_bf16(a0[m], b1f[n], accg[m][n], 0, 0, 0);
                    accu[m][n] = __builtin_amdgcn_mfma_f32_16x16x32_bf16(a0[m], b3f[n], accu[m][n], 0, 0, 0);
                }
        }
        // prefetch A frags for next kt, kk=0
        if (kt < HID / 64 - 1) {
#pragma unroll
            for (int m = 0; m < 4; ++m)
                a0[m] = *(const u16x8*)(xbb + aoff[m] + (kof + klane) * 2);
        }
        // kk = 32
        {
            bf16x8 b1f[4], b3f[4];
#pragma unroll
            for (int n = 0; n < 4; ++n) {
                b1f[n] = *(const bf16x8*)(lB1 + (n * 16 + (lane & 15)) * 72 + 32 + klane);
                b3f[n] = *(const bf16x8*)(lB3 + (n * 16 + (lane & 15)) * 72 + 32 + klane);
            }
#pragma unroll
            for (int m = 0; m < 4; ++m)
#pragma unroll
                for (int n = 0; n < 4; ++n) {
                    accg[m][n] = __builtin_amdgcn_mfma_f32_16x16x32_bf16(a1[m], b1f[n], accg[m][n], 0, 0, 0);
                    accu[m][n] = __builtin_amdgcn_mfma_f32_16x16x32_bf16(a1[m], b3f[n], accu[m][n], 0, 0, 0);
                }
        }
        __syncthreads();
    }

#pragma unroll
    for (int m = 0; m < 4; ++m)
#pragma unroll
        for (int n = 0; n < 4; ++n)
#pragma unroll
            for (int r = 0; r < 4; ++r) {
                int lr = wv * 64 + m * 16 + (lane >> 4) * 4 + r;
                if (rbase + lr < cnt) {
                    float g = accg[m][n][r], u = accu[m][n][r];
                    float s = g / (1.f + __expf(-g));
                    int col = fbase + n * 16 + (lane & 15);
                    act[(size_t)(obase + rbase + lr) * FF + col] = f2bf(s * u);
                }
            }
}

// ---------------- GEMM2: y[z] = act @ w2^T  (BM=256, BN=128, split-K=2) ----------------
__global__ __launch_bounds__(512, 2) void k_gemm2(
    const unsigned short* __restrict__ act, const float* __restrict__ w2,
    const int* __restrict__ counts, const int* __restrict__ offsets,
    const int* __restrict__ tl2e, const int* __restrict__ tl2m,
    const int* __restrict__ tilecnt, float* __restrict__ y)
{
    int by = blockIdx.y;
    if (by >= tilecnt[1]) return;
    int e = tl2e[by];
    int rbase = tl2m[by] * 256;
    int cnt = counts[e], obase = offsets[e];
    int hbase = blockIdx.x * 128;
    int z = blockIdx.z;
    const int kb0 = z * (FF / 2);     // 1792
    const int KS = FF / 2 / 64;       // 28

    __shared__ __align__(16) unsigned short lB[128 * 72];

    int tid = threadIdx.x, lane = tid & 63, wv = tid >> 6;
    int klane = (lane >> 4) * 8;

    int rbr = tid >> 2, cbc = (tid & 3) * 16;
    const float* pb = w2 + ((size_t)e * HID + hbase + rbr) * FF + kb0 + cbc;

    const char* actb = (const char*)act;
    unsigned int aoff[2];
#pragma unroll
    for (int m = 0; m < 2; ++m) {
        int r = obase + rbase + wv * 32 + m * 16 + (lane & 15);
        if (r > 4095) r = 4095;
        aoff[m] = (unsigned int)r * (FF * 2);
    }

    f32x4 acc[2][8];
#pragma unroll
    for (int m = 0; m < 2; ++m)
#pragma unroll
        for (int n = 0; n < 8; ++n) acc[m][n] = (f32x4){0.f, 0.f, 0.f, 0.f};

    float4 rw0 = *(const float4*)(pb);
    float4 rw1 = *(const float4*)(pb + 4);
    float4 rw2 = *(const float4*)(pb + 8);
    float4 rw3 = *(const float4*)(pb + 12);
    u16x8 a0[2], a1[2];
#pragma unroll
    for (int m = 0; m < 2; ++m)
        a0[m] = *(const u16x8*)(actb + aoff[m] + (kb0 + klane) * 2);

    for (int kt = 0; kt < KS; ++kt) {
        uint2 p;
        p.x = pack2(rw0.x, rw0.y); p.y = pack2(rw0.z, rw0.w);
        *(uint2*)(lB + rbr * 72 + cbc) = p;
        p.x = pack2(rw1.x, rw1.y); p.y = pack2(rw1.z, rw1.w);
        *(uint2*)(lB + rbr * 72 + cbc + 4) = p;
        p.x = pack2(rw2.x, rw2.y); p.y = pack2(rw2.z, rw2.w);
        *(uint2*)(lB + rbr * 72 + cbc + 8) = p;
        p.x = pack2(rw3.x, rw3.y); p.y = pack2(rw3.z, rw3.w);
        *(uint2*)(lB + rbr * 72 + cbc + 12) = p;
        __syncthreads();

        int kof = (kt + 1) * 64;
        if (kt < KS - 1) {
            rw0 = *(const float4*)(pb + kof);
            rw1 = *(const float4*)(pb + kof + 4);
            rw2 = *(const float4*)(pb + kof + 8);
            rw3 = *(const float4*)(pb + kof + 12);
        }
#pragma unroll
        for (int m = 0; m < 2; ++m)
            a1[m] = *(const u16x8*)(actb + aoff[m] + (kb0 + kt * 64 + 32 + klane) * 2);
        // kk = 0
        {
            bf16x8 bf[8];
#pragma unroll
            for (int n = 0; n < 8; ++n)
                bf[n] = *(const bf16x8*)(lB + (n * 16 + (lane & 15)) * 72 + klane);
#pragma unroll
            for (int m = 0; m < 2; ++m)
#pragma unroll
                for (int n = 0; n < 8; ++n)
                    acc[m][n] = __builtin_amdgcn_mfma_f32_16x16x32_bf16(a0[m], bf[n], acc[m][n], 0, 0, 0);
        }
        if (kt < KS - 1) {
#pragma unroll
            for (int m = 0; m < 2; ++m)
                a0[m] = *(const u16x8*)(actb + aoff[m] + (kb0 + kof + klane) * 2);
        }
        // kk = 32
        {
            bf16x8 bf[8];
#pragma unroll
            for (int n = 0; n < 8; ++n)
                bf[n] = *(const bf16x8*)(lB + (n * 16 + (lane & 15)) * 72 + 32 + klane);
#pragma unroll
            for (int m = 0; m < 2; ++m)
#pragma unroll
                for (int n = 0; n < 8; ++n)
                    acc[m][n] = __builtin_amdgcn_mfma_f32_16x16x32_bf16(a1[m], bf[n], acc[m][n], 0, 0, 0);
        }
        __syncthreads();
    }

    float* yz = y + (size_t)z * (T_TOK * TOPK * HID);
#pragma unroll
    for (int m = 0; m < 2; ++m)
#pragma unroll
        for (int n = 0; n < 8; ++n)
#pragma unroll
            for (int r = 0; r < 4; ++r) {
                int lr = wv * 32 + m * 16 + (lane >> 4) * 4 + r;
                if (rbase + lr < cnt) {
                    int col = hbase + n * 16 + (lane & 15);
                    yz[(size_t)(obase + rbase + lr) * HID + col] = acc[m][n][r];
                }
            }
}

// ---------------- combine ----------------
__global__ void k_combine(const float* __restrict__ y, const int* __restrict__ slotrow,
                          const float* __restrict__ topkw, float* __restrict__ out) {
    int j = blockIdx.x * blockDim.x + threadIdx.x;
    int t = j >> 8, c = j & 255;
    int r0 = slotrow[2 * t], r1 = slotrow[2 * t + 1];
    float w0 = topkw[2 * t], w1 = topkw[2 * t + 1];
    const float4* y0 = (const float4*)y;
    const float4* y1 = (const float4*)(y + (size_t)T_TOK * TOPK * HID);
    float4 a0 = y0[(size_t)r0 * 256 + c], a1 = y1[(size_t)r0 * 256 + c];
    float4 b0 = y0[(size_t)r1 * 256 + c], b1 = y1[(size_t)r1 * 256 + c];
    float4 o;
    o.x = w0 * (a0.x + a1.x) + w1 * (b0.x + b1.x);
    o.y = w0 * (a0.y + a1.y) + w1 * (b0.y + b1.y);
    o.z = w0 * (a0.z + a1.z) + w1 * (b0.z + b1.z);
    o.w = w0 * (a0.w + a1.w) + w1 * (b0.w + b1.w);
    ((float4*)out)[j] = o;
}

extern "C" void kernel_launch(void* const* d_in, const int* in_sizes, int n_in,
                              void* d_out, int out_size, void* d_ws, size_t ws_size,
                              hipStream_t stream) {
    const float* x  = (const float*)d_in[0];
    const float* gw = (const float*)d_in[1];
    const float* w1 = (const float*)d_in[2];
    const float* w3 = (const float*)d_in[3];
    const float* w2 = (const float*)d_in[4];
    float* out = (float*)d_out;

    char* ws = (char*)d_ws;
    int*   counts   = (int*)(ws + WS_COUNTS);
    int*   offsets  = (int*)(ws + WS_OFFSETS);
    int*   tilecnt  = (int*)(ws + WS_TILECNT);
    int*   tl1e     = (int*)(ws + WS_TLE1);
    int*   tl1m     = (int*)(ws + WS_TLM1);
    int*   tl2e     = (int*)(ws + WS_TLE2);
    int*   tl2m     = (int*)(ws + WS_TLM2);
    int*   topki    = (int*)(ws + WS_TOPKI);
    float* topkw    = (float*)(ws + WS_TOPKW);
    int*   slotpos  = (int*)(ws + WS_SLOTPOS);
    int*   slotrow  = (int*)(ws + WS_SLOTROW);
    int*   routetok = (int*)(ws + WS_ROUTETOK);
    unsigned short* xb   = (unsigned short*)(ws + WS_XBF);
    unsigned short* actb = (unsigned short*)(ws + WS_ACT);
    float* yb = (float*)(ws + WS_Y);

    hipMemsetAsync(counts, 0, 64, stream);
    k_router<<<T_TOK / 4, 256, 0, stream>>>(x, gw, xb, counts, topki, topkw, slotpos);
    k_prefix<<<1, 64, 0, stream>>>(counts, offsets, tl1e, tl1m, tl2e, tl2m, tilecnt);
    k_fill<<<16, 256, 0, stream>>>(topki, slotpos, offsets, routetok, slotrow);
    k_gemm1<<<dim3(FF / 64, 16, 1), 512, 0, stream>>>(xb, w1, w3, counts, offsets, routetok, tl1e, tl1m, tilecnt, actb);
    k_gemm2<<<dim3(HID / 128, 24, 2), 512, 0, stream>>>(actb, w2, counts, offsets, tl2e, tl2m, tilecnt, yb);
    k_combine<<<2048, 256, 0, stream>>>(yb, slotrow, topkw, out);
}

// Round 4
// 292.258 us; speedup vs baseline: 1.2165x; 1.2165x over previous
//
#include <hip/hip_runtime.h>
#include <hip/hip_bf16.h>

// Problem constants
#define T_TOK 2048
#define HID   1024
#define FF    3584
#define NE    8
#define TOPK  2
#define GRIDY 24          // >= max tiles at BM=256: 16 + 7

typedef __bf16 bf16x8 __attribute__((ext_vector_type(8)));
typedef float  f32x4  __attribute__((ext_vector_type(4)));
typedef unsigned short u16x8 __attribute__((ext_vector_type(8)));

// ---- workspace layout (bytes) ----
#define WS_COUNTS   0u
#define WS_OFFSETS  64u
#define WS_TILECNT  128u          // int[1]
#define WS_TLE      256u          // int[64]
#define WS_TLM      512u          // int[64]
#define WS_TOPKI    4096u         // int[4096]
#define WS_TOPKW    20480u        // float[4096]
#define WS_SLOTPOS  36864u        // int[4096]
#define WS_SLOTROW  53248u        // int[4096]
#define WS_ROUTETOK 69632u        // int[4096]
#define WS_XG       131072u                           // ushort[4096*1024] (8 MB)
#define WS_ACT      (WS_XG + 4096u*1024u*2u)          // ushort[4096*3584] (29.4 MB)
#define WS_Y        (WS_ACT + 4096u*3584u*2u)         // float[2*4096*1024] (32 MB)
// total ~69.5 MB

static __device__ __forceinline__ unsigned short f2bf(float f) {
    unsigned int u = __builtin_bit_cast(unsigned int, f);
    u += 0x7FFFu + ((u >> 16) & 1u);   // RNE
    return (unsigned short)(u >> 16);
}
static __device__ __forceinline__ unsigned int pack2(float a, float b) {
    unsigned int ua = __builtin_bit_cast(unsigned int, a) + 0x8000u;
    unsigned int ub = __builtin_bit_cast(unsigned int, b) + 0x8000u;
    return (ua >> 16) | (ub & 0xFFFF0000u);
}

// ---------------- router ----------------
__global__ __launch_bounds__(256) void k_router(
    const float* __restrict__ x, const float* __restrict__ gw,
    int* __restrict__ counts, int* __restrict__ topki,
    float* __restrict__ topkw, int* __restrict__ slotpos)
{
    int t = blockIdx.x * 4 + (threadIdx.x >> 6);
    int l = threadIdx.x & 63;
    const float* xr = x + (size_t)t * HID;
    float acc[NE];
#pragma unroll
    for (int e = 0; e < NE; ++e) acc[e] = 0.f;
#pragma unroll
    for (int i = 0; i < 4; ++i) {
        int h = l * 4 + i * 256;
        float4 xv = *(const float4*)(xr + h);
#pragma unroll
        for (int e = 0; e < NE; ++e) {
            float4 g = *(const float4*)(gw + e * HID + h);
            acc[e] += xv.x * g.x + xv.y * g.y + xv.z * g.z + xv.w * g.w;
        }
    }
#pragma unroll
    for (int e = 0; e < NE; ++e) {
#pragma unroll
        for (int off = 32; off; off >>= 1) acc[e] += __shfl_xor(acc[e], off);
    }
    if (l == 0) {
        float best = -1e30f, second = -1e30f;
        int bi = 0, si = 0;
#pragma unroll
        for (int e = 0; e < NE; ++e) {
            float v = acc[e];
            if (v > best) { second = best; si = bi; best = v; bi = e; }
            else if (v > second) { second = v; si = e; }
        }
        float w0 = 1.f / (1.f + __expf(second - best));
        float w1 = 1.f - w0;
        topki[2 * t] = bi;  topki[2 * t + 1] = si;
        topkw[2 * t] = w0;  topkw[2 * t + 1] = w1;
        slotpos[2 * t]     = atomicAdd(&counts[bi], 1);
        slotpos[2 * t + 1] = atomicAdd(&counts[si], 1);
    }
}

// ---------------- prefix + compact tile list (BM=256) ----------------
__global__ void k_prefix(const int* __restrict__ counts, int* __restrict__ offsets,
                         int* __restrict__ tle, int* __restrict__ tlm,
                         int* __restrict__ tilecnt) {
    if (threadIdx.x == 0) {
        int o = 0;
#pragma unroll
        for (int e = 0; e < NE; ++e) { offsets[e] = o; o += counts[e]; }
        int n = 0;
        for (int e = 0; e < NE; ++e) {
            int t = (counts[e] + 255) >> 8;
            for (int i = 0; i < t; ++i) { tle[n] = e; tlm[n] = i; ++n; }
        }
        tilecnt[0] = n;
    }
}

// ---------------- fill routing arrays ----------------
__global__ void k_fill(const int* __restrict__ topki, const int* __restrict__ slotpos,
                       const int* __restrict__ offsets, int* __restrict__ routetok,
                       int* __restrict__ slotrow) {
    int j = blockIdx.x * blockDim.x + threadIdx.x;
    if (j >= T_TOK * TOPK) return;
    int e = topki[j];
    int row = offsets[e] + slotpos[j];
    routetok[row] = j >> 1;
    slotrow[j] = row;
}

// ---------------- gather + convert: xg[row] = bf16(x[routetok[row]]) ----------------
__global__ void k_gather(const float* __restrict__ x, const int* __restrict__ routetok,
                         unsigned short* __restrict__ xg) {
    int j = blockIdx.x * blockDim.x + threadIdx.x;   // 4096*256 threads
    int r = j >> 8;                                  // 256 float4-groups per row
    int c = (j & 255) * 4;
    int tok = routetok[r];
    float4 v = *(const float4*)(x + (size_t)tok * HID + c);
    ushort4 o;
    o.x = f2bf(v.x); o.y = f2bf(v.y); o.z = f2bf(v.z); o.w = f2bf(v.w);
    *(ushort4*)(xg + (size_t)r * HID + c) = o;
}

// ---------------- GEMM1: act = silu(Xg@w1^T) * (Xg@w3^T) ----------------
// BM=256, BN=64 (both w1 and w3), BK=64, 8 waves, LDS-staged A and B.
__global__ __launch_bounds__(512, 4) void k_gemm1(
    const unsigned short* __restrict__ xg, const float* __restrict__ w1,
    const float* __restrict__ w3, const int* __restrict__ counts,
    const int* __restrict__ offsets, const int* __restrict__ tle,
    const int* __restrict__ tlm, const int* __restrict__ tilecnt,
    unsigned short* __restrict__ act)
{
    int by = blockIdx.y;
    if (by >= tilecnt[0]) return;
    int e = tle[by];
    int rbase = tlm[by] * 256;
    int cnt = counts[e], obase = offsets[e];
    int fbase = blockIdx.x * 64;

    __shared__ __align__(16) unsigned short lA[256 * 72];
    __shared__ __align__(16) unsigned short lB1[64 * 72];
    __shared__ __align__(16) unsigned short lB3[64 * 72];

    int tid = threadIdx.x;
    // staging addresses
    const int ra0 = tid >> 3, ca = (tid & 7) * 8;      // A: 64 rows/round, 4 rounds
    const int rb0 = tid >> 4, cb = (tid & 15) * 4;     // B: 32 rows/round, 2 rounds
    const unsigned short* pa[4];
#pragma unroll
    for (int i = 0; i < 4; ++i) {
        int r = obase + rbase + ra0 + 64 * i;
        if (r > 4095) r = 4095;
        pa[i] = xg + (size_t)r * HID + ca;
    }
    const float* w1e = w1 + ((size_t)e * FF + fbase) * HID;
    const float* w3e = w3 + ((size_t)e * FF + fbase) * HID;
    const float* pb1[2];
    const float* pb3[2];
#pragma unroll
    for (int i = 0; i < 2; ++i) {
        pb1[i] = w1e + (size_t)(rb0 + 32 * i) * HID + cb;
        pb3[i] = w3e + (size_t)(rb0 + 32 * i) * HID + cb;
    }

    int lane = tid & 63, wv = tid >> 6, wr = wv >> 1, wc = wv & 1;
    int klane = (lane >> 4) * 8;
    f32x4 accg[4][2], accu[4][2];
#pragma unroll
    for (int m = 0; m < 4; ++m)
#pragma unroll
        for (int n = 0; n < 2; ++n) {
            accg[m][n] = (f32x4){0.f, 0.f, 0.f, 0.f};
            accu[m][n] = (f32x4){0.f, 0.f, 0.f, 0.f};
        }

    u16x8 ra[4]; float4 r1[2], r3[2];
#pragma unroll
    for (int i = 0; i < 4; ++i) ra[i] = *(const u16x8*)(pa[i]);
#pragma unroll
    for (int i = 0; i < 2; ++i) { r1[i] = *(const float4*)(pb1[i]); r3[i] = *(const float4*)(pb3[i]); }

    for (int kt = 0; kt < HID / 64; ++kt) {
#pragma unroll
        for (int i = 0; i < 4; ++i)
            *(u16x8*)(lA + (ra0 + 64 * i) * 72 + ca) = ra[i];
#pragma unroll
        for (int i = 0; i < 2; ++i) {
            uint2 p;
            p.x = pack2(r1[i].x, r1[i].y); p.y = pack2(r1[i].z, r1[i].w);
            *(uint2*)(lB1 + (rb0 + 32 * i) * 72 + cb) = p;
            p.x = pack2(r3[i].x, r3[i].y); p.y = pack2(r3[i].z, r3[i].w);
            *(uint2*)(lB3 + (rb0 + 32 * i) * 72 + cb) = p;
        }
        __syncthreads();
        if (kt < HID / 64 - 1) {
            int kof = (kt + 1) * 64;
#pragma unroll
            for (int i = 0; i < 4; ++i) ra[i] = *(const u16x8*)(pa[i] + kof);
#pragma unroll
            for (int i = 0; i < 2; ++i) {
                r1[i] = *(const float4*)(pb1[i] + kof);
                r3[i] = *(const float4*)(pb3[i] + kof);
            }
        }
#pragma unroll
        for (int kk = 0; kk < 64; kk += 32) {
            int kcol = kk + klane;
            bf16x8 a[4], b1[2], b3[2];
#pragma unroll
            for (int m = 0; m < 4; ++m)
                a[m] = *(const bf16x8*)(lA + (wr * 64 + m * 16 + (lane & 15)) * 72 + kcol);
#pragma unroll
            for (int n = 0; n < 2; ++n) {
                b1[n] = *(const bf16x8*)(lB1 + (wc * 32 + n * 16 + (lane & 15)) * 72 + kcol);
                b3[n] = *(const bf16x8*)(lB3 + (wc * 32 + n * 16 + (lane & 15)) * 72 + kcol);
            }
#pragma unroll
            for (int m = 0; m < 4; ++m)
#pragma unroll
                for (int n = 0; n < 2; ++n) {
                    accg[m][n] = __builtin_amdgcn_mfma_f32_16x16x32_bf16(a[m], b1[n], accg[m][n], 0, 0, 0);
                    accu[m][n] = __builtin_amdgcn_mfma_f32_16x16x32_bf16(a[m], b3[n], accu[m][n], 0, 0, 0);
                }
        }
        __syncthreads();
    }

#pragma unroll
    for (int m = 0; m < 4; ++m)
#pragma unroll
        for (int n = 0; n < 2; ++n)
#pragma unroll
            for (int r = 0; r < 4; ++r) {
                int lr = wr * 64 + m * 16 + (lane >> 4) * 4 + r;
                if (rbase + lr < cnt) {
                    float g = accg[m][n][r], u = accu[m][n][r];
                    float s = g / (1.f + __expf(-g));
                    int col = fbase + wc * 32 + n * 16 + (lane & 15);
                    act[(size_t)(obase + rbase + lr) * FF + col] = f2bf(s * u);
                }
            }
}

// ---------------- GEMM2: y[z] = act @ w2^T  (BM=256, BN=64, split-K=2) ----------------
__global__ __launch_bounds__(512, 4) void k_gemm2(
    const unsigned short* __restrict__ act, const float* __restrict__ w2,
    const int* __restrict__ counts, const int* __restrict__ offsets,
    const int* __restrict__ tle, const int* __restrict__ tlm,
    const int* __restrict__ tilecnt, float* __restrict__ y)
{
    int by = blockIdx.y;
    if (by >= tilecnt[0]) return;
    int e = tle[by];
    int rbase = tlm[by] * 256;
    int cnt = counts[e], obase = offsets[e];
    int hbase = blockIdx.x * 64;
    int z = blockIdx.z;
    const int kb0 = z * (FF / 2);
    const int KS = FF / 2 / 64;       // 28

    __shared__ __align__(16) unsigned short lA[256 * 72];
    __shared__ __align__(16) unsigned short lB[64 * 72];

    int tid = threadIdx.x;
    const int ra0 = tid >> 3, ca = (tid & 7) * 8;
    const int rb0 = tid >> 4, cb = (tid & 15) * 4;
    const unsigned short* pa[4];
#pragma unroll
    for (int i = 0; i < 4; ++i) {
        int r = obase + rbase + ra0 + 64 * i;
        if (r > 4095) r = 4095;
        pa[i] = act + (size_t)r * FF + kb0 + ca;
    }
    const float* w2e = w2 + ((size_t)e * HID + hbase) * FF;
    const float* pb[2];
#pragma unroll
    for (int i = 0; i < 2; ++i)
        pb[i] = w2e + (size_t)(rb0 + 32 * i) * FF + kb0 + cb;

    int lane = tid & 63, wv = tid >> 6, wr = wv >> 1, wc = wv & 1;
    int klane = (lane >> 4) * 8;
    f32x4 acc[4][2];
#pragma unroll
    for (int m = 0; m < 4; ++m)
#pragma unroll
        for (int n = 0; n < 2; ++n) acc[m][n] = (f32x4){0.f, 0.f, 0.f, 0.f};

    u16x8 ra[4]; float4 rw[2];
#pragma unroll
    for (int i = 0; i < 4; ++i) ra[i] = *(const u16x8*)(pa[i]);
#pragma unroll
    for (int i = 0; i < 2; ++i) rw[i] = *(const float4*)(pb[i]);

    for (int kt = 0; kt < KS; ++kt) {
#pragma unroll
        for (int i = 0; i < 4; ++i)
            *(u16x8*)(lA + (ra0 + 64 * i) * 72 + ca) = ra[i];
#pragma unroll
        for (int i = 0; i < 2; ++i) {
            uint2 p;
            p.x = pack2(rw[i].x, rw[i].y); p.y = pack2(rw[i].z, rw[i].w);
            *(uint2*)(lB + (rb0 + 32 * i) * 72 + cb) = p;
        }
        __syncthreads();
        if (kt < KS - 1) {
            int kof = (kt + 1) * 64;
#pragma unroll
            for (int i = 0; i < 4; ++i) ra[i] = *(const u16x8*)(pa[i] + kof);
#pragma unroll
            for (int i = 0; i < 2; ++i) rw[i] = *(const float4*)(pb[i] + kof);
        }
#pragma unroll
        for (int kk = 0; kk < 64; kk += 32) {
            int kcol = kk + klane;
            bf16x8 a[4], b[2];
#pragma unroll
            for (int m = 0; m < 4; ++m)
                a[m] = *(const bf16x8*)(lA + (wr * 64 + m * 16 + (lane & 15)) * 72 + kcol);
#pragma unroll
            for (int n = 0; n < 2; ++n)
                b[n] = *(const bf16x8*)(lB + (wc * 32 + n * 16 + (lane & 15)) * 72 + kcol);
#pragma unroll
            for (int m = 0; m < 4; ++m)
#pragma unroll
                for (int n = 0; n < 2; ++n)
                    acc[m][n] = __builtin_amdgcn_mfma_f32_16x16x32_bf16(a[m], b[n], acc[m][n], 0, 0, 0);
        }
        __syncthreads();
    }

    float* yz = y + (size_t)z * (T_TOK * TOPK * HID);
#pragma unroll
    for (int m = 0; m < 4; ++m)
#pragma unroll
        for (int n = 0; n < 2; ++n)
#pragma unroll
            for (int r = 0; r < 4; ++r) {
                int lr = wr * 64 + m * 16 + (lane >> 4) * 4 + r;
                if (rbase + lr < cnt) {
                    int col = hbase + wc * 32 + n * 16 + (lane & 15);
                    yz[(size_t)(obase + rbase + lr) * HID + col] = acc[m][n][r];
                }
            }
}

// ---------------- combine ----------------
__global__ void k_combine(const float* __restrict__ y, const int* __restrict__ slotrow,
                          const float* __restrict__ topkw, float* __restrict__ out) {
    int j = blockIdx.x * blockDim.x + threadIdx.x;
    int t = j >> 8, c = j & 255;
    int r0 = slotrow[2 * t], r1 = slotrow[2 * t + 1];
    float w0 = topkw[2 * t], w1 = topkw[2 * t + 1];
    const float4* y0 = (const float4*)y;
    const float4* y1 = (const float4*)(y + (size_t)T_TOK * TOPK * HID);
    float4 a0 = y0[(size_t)r0 * 256 + c], a1 = y1[(size_t)r0 * 256 + c];
    float4 b0 = y0[(size_t)r1 * 256 + c], b1 = y1[(size_t)r1 * 256 + c];
    float4 o;
    o.x = w0 * (a0.x + a1.x) + w1 * (b0.x + b1.x);
    o.y = w0 * (a0.y + a1.y) + w1 * (b0.y + b1.y);
    o.z = w0 * (a0.z + a1.z) + w1 * (b0.z + b1.z);
    o.w = w0 * (a0.w + a1.w) + w1 * (b0.w + b1.w);
    ((float4*)out)[j] = o;
}

extern "C" void kernel_launch(void* const* d_in, const int* in_sizes, int n_in,
                              void* d_out, int out_size, void* d_ws, size_t ws_size,
                              hipStream_t stream) {
    const float* x  = (const float*)d_in[0];
    const float* gw = (const float*)d_in[1];
    const float* w1 = (const float*)d_in[2];
    const float* w3 = (const float*)d_in[3];
    const float* w2 = (const float*)d_in[4];
    float* out = (float*)d_out;

    char* ws = (char*)d_ws;
    int*   counts   = (int*)(ws + WS_COUNTS);
    int*   offsets  = (int*)(ws + WS_OFFSETS);
    int*   tilecnt  = (int*)(ws + WS_TILECNT);
    int*   tle      = (int*)(ws + WS_TLE);
    int*   tlm      = (int*)(ws + WS_TLM);
    int*   topki    = (int*)(ws + WS_TOPKI);
    float* topkw    = (float*)(ws + WS_TOPKW);
    int*   slotpos  = (int*)(ws + WS_SLOTPOS);
    int*   slotrow  = (int*)(ws + WS_SLOTROW);
    int*   routetok = (int*)(ws + WS_ROUTETOK);
    unsigned short* xg   = (unsigned short*)(ws + WS_XG);
    unsigned short* actb = (unsigned short*)(ws + WS_ACT);
    float* yb = (float*)(ws + WS_Y);

    hipMemsetAsync(counts, 0, 64, stream);
    k_router<<<T_TOK / 4, 256, 0, stream>>>(x, gw, counts, topki, topkw, slotpos);
    k_prefix<<<1, 64, 0, stream>>>(counts, offsets, tle, tlm, tilecnt);
    k_fill<<<16, 256, 0, stream>>>(topki, slotpos, offsets, routetok, slotrow);
    k_gather<<<4096, 256, 0, stream>>>(x, routetok, xg);
    k_gemm1<<<dim3(FF / 64, GRIDY, 1), 512, 0, stream>>>(xg, w1, w3, counts, offsets, tle, tlm, tilecnt, actb);
    k_gemm2<<<dim3(HID / 64, GRIDY, 2), 512, 0, stream>>>(actb, w2, counts, offsets, tle, tlm, tilecnt, yb);
    k_combine<<<2048, 256, 0, stream>>>(yb, slotrow, topkw, out);
}